// Round 13
// baseline (185.845 us; speedup 1.0000x reference)
//
#include <hip/hip_runtime.h>

#define DIM 64
#define K_CODES 512
#define N_VEC 131072
#define CREP 16
#define DREP 64
#define Q_OFF 1
#define PERP_OFF 8388609
#define ENC_OFF 8388610

#define NF4_TOTAL 16777215      // float4 groups in enc body (enc+2 .. enc+67108862)
#define ENC_A_F4  9437184       // slice A: [0, ENC_A_F4) ~151 MB  (with dw)
#define ENC_A_BLOCKS 768
#define ENC_B_BLOCKS 768
#define DW_BLOCKS 512
#define QZ_BLOCKS 2048

using bfrag = __attribute__((ext_vector_type(8))) short;  // 8 bf16 = 4 VGPR
using ffrag = __attribute__((ext_vector_type(4))) float;  // 4 f32 acc

// Exact 3-way bf16 truncation split: x == x0 + x1 + x2.
__device__ __forceinline__ void split3(float x, short& h0, short& h1, short& h2)
{
    unsigned u0 = __float_as_uint(x);
    h0 = (short)(u0 >> 16);
    float r = x - __uint_as_float(u0 & 0xFFFF0000u);     // exact
    unsigned u1 = __float_as_uint(r);
    h1 = (short)(u1 >> 16);
    float r2 = r - __uint_as_float(u1 & 0xFFFF0000u);    // exact
    h2 = (short)(__float_as_uint(r2) >> 16);             // r2 fits bf16 exactly
}

// ---------------------------------------------------------------------------
// epack + ee fused, plus zeroing of crep/lossac.
// epack[((ct*2+db)*3+s)*64+lane]: code c = ct*16+(lane&15),
// d = db*32+(lane>>4)*8+0..7, split s. 192 KB, L2-resident.
// ---------------------------------------------------------------------------
__global__ __launch_bounds__(256) void epack_ee_kernel(
    const float* __restrict__ emb_w,
    bfrag* __restrict__ epack,
    float* __restrict__ ee,
    float* __restrict__ crep,
    float* __restrict__ lossac)
{
    __shared__ float part[2][16][8];
    const int tl = threadIdx.x;
    const int t = blockIdx.x * 256 + tl;            // 0..4095
    const int lane = t & 63;
    const int db = (t >> 6) & 1;
    const int ctl = tl >> 7;                        // 0..1 (block-local)
    const int ct = t >> 7;                          // 0..31
    const int r16 = lane & 15, quad = lane >> 4;
    const int c  = ct * 16 + r16;
    const int d0 = db * 32 + quad * 8;
    const float* src = emb_w + (size_t)c * DIM + d0;

    crep[t] = 0.f;
    crep[4096 + t] = 0.f;
    if (t == 0) lossac[0] = 0.f;

    bfrag f0, f1, f2;
    float ssum = 0.f;
#pragma unroll
    for (int j = 0; j < 8; ++j) {
        const float x = src[j];
        ssum = fmaf(x, x, ssum);
        short a, b, cc;
        split3(x, a, b, cc);
        f0[j] = a; f1[j] = b; f2[j] = cc;
    }
    const int base = (ct * 2 + db) * 3;
    epack[(base + 0) * 64 + lane] = f0;
    epack[(base + 1) * 64 + lane] = f1;
    epack[(base + 2) * 64 + lane] = f2;

    part[ctl][r16][db * 4 + quad] = ssum;
    __syncthreads();
    if (tl < 32) {
        const int cl = tl >> 4, r = tl & 15;
        float s = 0.f;
#pragma unroll
        for (int i = 0; i < 8; ++i) s += part[cl][r][i];
        ee[(blockIdx.x * 2 + cl) * 16 + r] = s;
    }
}

// ---------------------------------------------------------------------------
// argmin via 6-pass split-bf16 MFMA (unchanged from R12 best-known config).
// Wave owns 64 vectors; block = 4 waves = 256 vectors; grid 512.
// Prologue zeroes dwrep slice. Writes idx + counts into 16 replicas.
// ---------------------------------------------------------------------------
__global__ __launch_bounds__(256, 2) void argmin_mfma_kernel(
    const float* __restrict__ inputs,
    const bfrag* __restrict__ epack,
    const float* __restrict__ eeg,
    int* __restrict__ idx,
    float* __restrict__ counts_rep,
    float* __restrict__ dwrep)
{
    const int t = threadIdx.x;
    const int lane = t & 63;
    const int r16 = lane & 15;
    const int quad = lane >> 4;
    const size_t v0 = (size_t)blockIdx.x * 256 + (t >> 6) * 64;

    // ---- zero this block's 16 KB slice of dwrep (8 MB / 512 blocks) ----
    {
        float4* z4 = reinterpret_cast<float4*>(dwrep) + (size_t)blockIdx.x * 1024;
        const float4 z = make_float4(0.f, 0.f, 0.f, 0.f);
#pragma unroll
        for (int i = 0; i < 4; ++i) z4[i * 256 + t] = z;
    }

    // ---- load + exact-split X into A-fragments (96 VGPRs) ----
    bfrag xf[4][2][3];
#pragma unroll
    for (int rt = 0; rt < 4; ++rt)
#pragma unroll
        for (int db = 0; db < 2; ++db) {
            const float* src = inputs + (v0 + rt * 16 + r16) * DIM + db * 32 + quad * 8;
            const float4 va = *reinterpret_cast<const float4*>(src);
            const float4 vb = *reinterpret_cast<const float4*>(src + 4);
            float vals[8] = {va.x, va.y, va.z, va.w, vb.x, vb.y, vb.z, vb.w};
            bfrag f0, f1, f2;
#pragma unroll
            for (int j = 0; j < 8; ++j) {
                short a, b, c;
                split3(vals[j], a, b, c);
                f0[j] = a; f1[j] = b; f2[j] = c;
            }
            xf[rt][db][0] = f0; xf[rt][db][1] = f1; xf[rt][db][2] = f2;
        }

    float best[4][4];
    int bestk[4][4];
#pragma unroll
    for (int a = 0; a < 4; ++a)
#pragma unroll
        for (int b = 0; b < 4; ++b) { best[a][b] = 3.4e38f; bestk[a][b] = 0; }

    constexpr int PI[6] = {0, 0, 1, 0, 2, 1};
    constexpr int PJ[6] = {0, 1, 0, 2, 0, 1};

#pragma unroll 2
    for (int ct = 0; ct < 32; ++ct) {
        bfrag e[2][3];
#pragma unroll
        for (int db = 0; db < 2; ++db)
#pragma unroll
            for (int s = 0; s < 3; ++s)
                e[db][s] = epack[((ct * 2 + db) * 3 + s) * 64 + lane];
        const float eel = eeg[ct * 16 + r16];

        ffrag acc[4];
#pragma unroll
        for (int rt = 0; rt < 4; ++rt) acc[rt] = (ffrag){0.f, 0.f, 0.f, 0.f};

#pragma unroll
        for (int db = 0; db < 2; ++db)
#pragma unroll
            for (int p = 0; p < 6; ++p)
#pragma unroll
                for (int rt = 0; rt < 4; ++rt)
                    acc[rt] = __builtin_amdgcn_mfma_f32_16x16x32_bf16(
                        xf[rt][db][PI[p]], e[db][PJ[p]], acc[rt], 0, 0, 0);

        const int kc = ct * 16 + r16;
#pragma unroll
        for (int rt = 0; rt < 4; ++rt)
#pragma unroll
            for (int rg = 0; rg < 4; ++rg) {
                const float dist = fmaf(-2.f, acc[rt][rg], eel);
                if (dist < best[rt][rg]) { best[rt][rg] = dist; bestk[rt][rg] = kc; }
            }
    }

    // ---- cross-lane argmin over each 16-lane code group ----
#pragma unroll
    for (int rt = 0; rt < 4; ++rt)
#pragma unroll
        for (int rg = 0; rg < 4; ++rg) {
            float b = best[rt][rg];
            int k = bestk[rt][rg];
#pragma unroll
            for (int m = 1; m < 16; m <<= 1) {
                const float ob = __shfl_xor(b, m, 64);
                const int ok = __shfl_xor(k, m, 64);
                if (ob < b || (ob == b && ok < k)) { b = ob; k = ok; }
            }
            bestk[rt][rg] = k;
        }

    if (r16 == 0) {
        float* crep = counts_rep + (blockIdx.x & (CREP - 1)) * K_CODES;
#pragma unroll
        for (int rt = 0; rt < 4; ++rt)
#pragma unroll
            for (int rg = 0; rg < 4; ++rg) {
                const int v = rt * 16 + quad * 4 + rg;
                const int k = bestk[rt][rg];
                idx[v0 + v] = k;
                atomicAdd(&crep[k], 1.0f);
            }
    }
}

// ---------------------------------------------------------------------------
// enc body writer for float4 groups [g_lo, g_hi): one-hot values computed
// per element. Shared by mix1 (slice A) and mix2 (slice B).
// ---------------------------------------------------------------------------
__device__ __forceinline__ void enc_body_write(
    const int* __restrict__ idx, float* __restrict__ enc,
    int eb, int nblocks, size_t g_lo, size_t g_hi, int t)
{
    float4* body = reinterpret_cast<float4*>(enc + 2); // 16B-aligned
    const size_t stride = (size_t)nblocks * 256;
    for (size_t g = g_lo + (size_t)eb * 256 + t; g < g_hi; g += stride) {
        const size_t e0 = 4 * g + 2;                   // element index of .x
        const int r0 = (int)(e0 >> 9);
        const int r1 = (int)((e0 + 3) >> 9);
        const int i0 = idx[r0];
        const int i1 = (r1 != r0) ? idx[r1] : i0;
        float4 v;
        v.x = ((int)(e0 & 511) == i0) ? 1.f : 0.f;
        v.y = ((int)((e0 + 1) & 511) == (((e0 + 1) >> 9) == (size_t)r0 ? i0 : i1)) ? 1.f : 0.f;
        v.z = ((int)((e0 + 2) & 511) == (((e0 + 2) >> 9) == (size_t)r0 ? i0 : i1)) ? 1.f : 0.f;
        v.w = ((int)((e0 + 3) & 511) == (((e0 + 3) >> 9) == (size_t)r0 ? i0 : i1)) ? 1.f : 0.f;
        body[g] = v;
    }
}

// ---------------------------------------------------------------------------
// mix1: dw segment-sum (512 blocks) INTERLEAVED with enc slice A (768 blocks).
// Role by blockIdx % 5 ({0,1}=dw, {2,3,4}=enc) so both roles are co-resident
// per CU: enc's store-pipe work hides under dw's atomic latency.
// ---------------------------------------------------------------------------
__global__ __launch_bounds__(256) void mix1_kernel(
    const float* __restrict__ inputs,
    const int* __restrict__ idx,
    float* __restrict__ enc,
    float* __restrict__ dwrep)
{
    const int g = blockIdx.x / 5, r = blockIdx.x % 5;
    const int t = threadIdx.x;

    if (r < 2) {
        // ---------------- dw scatter: 256 vectors per block ----------------
        __shared__ int sIdx[256];
        const int bid = g * 2 + r;                     // 0..511
        const size_t vbase = (size_t)bid * 256;
        sIdx[t] = idx[vbase + t];
        __syncthreads();
        const int w = t >> 6, lane = t & 63;
        const int v0 = w * 64;
#pragma unroll 4
        for (int j = 0; j < 64; ++j) {
            const int v = v0 + j;
            const int k = sIdx[v];
            const float xv = inputs[(vbase + v) * DIM + lane];
            atomicAdd(&dwrep[((size_t)(v & (DREP - 1)) << 15) + (k << 6) + lane], xv);
        }
    } else {
        // ---------------- enc slice A ----------------
        const int eb = g * 3 + (r - 2);                // 0..767
        enc_body_write(idx, enc, eb, ENC_A_BLOCKS, 0, ENC_A_F4, t);
        if (eb == 0 && t == 0) {
            const int k0 = idx[0];
            enc[0] = (k0 == 0) ? 1.f : 0.f;
            enc[1] = (k0 == 1) ? 1.f : 0.f;
        }
    }
}

// ---------------------------------------------------------------------------
// emaB fused (absorbs emaA): every block redundantly reduces the 16x512
// counts replicas (32 KB L2), builds all-512 smoothed cs in LDS, block 0
// also writes perplexity. Then codebook update for its 4 codes.
// ---------------------------------------------------------------------------
__global__ __launch_bounds__(256) void emaBF_kernel(
    const float* __restrict__ counts_rep,
    const float* __restrict__ ema_cs,
    const float* __restrict__ dwrep,
    const float* __restrict__ ema_w,
    float* __restrict__ new_emb,
    float* __restrict__ perp_out)
{
    __shared__ float scs[K_CODES];
    __shared__ float red[256];
    const int t = threadIdx.x;

    // counts for codes 2t, 2t+1
    float c0 = 0.f, c1 = 0.f;
#pragma unroll
    for (int r = 0; r < CREP; ++r) {
        c0 += counts_rep[r * K_CODES + 2 * t];
        c1 += counts_rep[r * K_CODES + 2 * t + 1];
    }
    const float cs0 = ema_cs[2 * t] * 0.99f + 0.01f * c0;
    const float cs1 = ema_cs[2 * t + 1] * 0.99f + 0.01f * c1;

    red[t] = cs0 + cs1;
    __syncthreads();
    for (int s = 128; s > 0; s >>= 1) {
        if (t < s) red[t] += red[t + s];
        __syncthreads();
    }
    const float n = red[0];
    __syncthreads();

    const float scale = n / (n + (float)K_CODES * 1e-5f);
    scs[2 * t]     = (cs0 + 1e-5f) * scale;
    scs[2 * t + 1] = (cs1 + 1e-5f) * scale;

    if (blockIdx.x == 0) {
        const float p0 = c0 * (1.0f / (float)N_VEC);
        const float p1 = c1 * (1.0f / (float)N_VEC);
        red[t] = p0 * logf(p0 + 1e-10f) + p1 * logf(p1 + 1e-10f);
        __syncthreads();
        for (int s = 128; s > 0; s >>= 1) {
            if (t < s) red[t] += red[t + s];
            __syncthreads();
        }
        if (t == 0) perp_out[0] = expf(-red[0]);
    }
    __syncthreads();

    // codebook update: block covers codes [4b, 4b+4)
    const int k = blockIdx.x * 4 + (t >> 6);
    const int e = k * DIM + (t & 63);
    float dwv = 0.f;
#pragma unroll
    for (int r = 0; r < DREP; ++r) dwv += dwrep[((size_t)r << 15) + e];
    const float v = ema_w[e] * 0.99f + 0.01f * dwv;
    new_emb[e] = v / scs[k];
}

// ---------------------------------------------------------------------------
// mix2: quantize (2048 blocks) INTERLEAVED with enc slice B (768 blocks).
// Role by blockIdx % 11 ({0..7}=quantize, {8,9,10}=enc).
// ---------------------------------------------------------------------------
__global__ __launch_bounds__(256) void mix2_kernel(
    const float* __restrict__ inputs,
    const int* __restrict__ idx,
    const float* __restrict__ new_emb,
    float* __restrict__ out_q,
    float* __restrict__ loss_accum,
    float* __restrict__ enc)
{
    const int g = blockIdx.x / 11, r = blockIdx.x % 11;
    const int t = threadIdx.x;

    if (r < 8) {
        // ---------------- quantize: gather + ST + NHWC->NCHW + loss --------
        __shared__ int sIdx[64];
        __shared__ float tile[DIM][65];
        __shared__ float wsum[4];

        const int bh = g * 8 + r;                      // 0..2047
        const int b = bh >> 6, h = bh & 63;

        if (t < 64) sIdx[t] = idx[bh * 64 + t];
        __syncthreads();

        const float* inRow = inputs + (size_t)bh * 64 * DIM;
        const int d = t & 63;
        const int wg = t >> 6;
        float lsum = 0.f;
#pragma unroll
        for (int p = 0; p < 16; ++p) {
            const int w = wg * 16 + p;
            const float xv = inRow[w * DIM + d];
            const float qv = new_emb[sIdx[w] * DIM + d];
            const float diff = qv - xv;
            tile[d][w] = xv + diff;
            lsum = fmaf(diff, diff, lsum);
        }
        __syncthreads();

        const int w2 = t & 63;
        const int dg = t >> 6;
#pragma unroll
        for (int p = 0; p < 16; ++p) {
            const int d2 = dg * 16 + p;
            out_q[(((size_t)b * DIM + d2) * 64 + h) * 64 + w2] = tile[d2][w2];
        }

        for (int off = 32; off > 0; off >>= 1) lsum += __shfl_down(lsum, off);
        if ((t & 63) == 0) wsum[t >> 6] = lsum;
        __syncthreads();
        if (t == 0) atomicAdd(loss_accum, (wsum[0] + wsum[1]) + (wsum[2] + wsum[3]));
    } else {
        // ---------------- enc slice B ----------------
        const int eb = g * 3 + (r - 8);                // 0..767
        enc_body_write(idx, enc, eb, ENC_B_BLOCKS, ENC_A_F4, NF4_TOTAL, t);
        if (eb == 0 && t == 0) {
            const int kL = idx[N_VEC - 1];
            enc[67108862] = (kL == 510) ? 1.f : 0.f;
            enc[67108863] = (kL == 511) ? 1.f : 0.f;
        }
    }
}

__global__ void finalize_kernel(const float* __restrict__ loss_accum,
                                float* __restrict__ out_loss)
{
    out_loss[0] = 0.25f * (loss_accum[0] / 8388608.0f);
}

// ---------------------------------------------------------------------------
extern "C" void kernel_launch(void* const* d_in, const int* in_sizes, int n_in,
                              void* d_out, int out_size, void* d_ws, size_t ws_size,
                              hipStream_t stream)
{
    const float* inputs = (const float*)d_in[0];
    const float* emb_w  = (const float*)d_in[1];
    const float* ema_cs = (const float*)d_in[2];
    const float* ema_w  = (const float*)d_in[3];
    float* out = (float*)d_out;
    float* ws  = (float*)d_ws;

    // ws layout (f32 offsets):
    int*   idxbuf  = (int*)ws;              // [0, 131072)
    float* crep    = ws + 131072;           // [131072, 139264)  16x512
    float* lossac  = ws + 139264;           // [139264]
    float* csbuf   = ws + 139265;           // (unused now)
    float* eebuf   = ws + 139777;           // [139777, 140289)
    float* nemb    = ws + 140289;           // [140289, 173057)
    bfrag* epack   = (bfrag*)(ws + 173060); // 192 KB, 16B-aligned
    (void)csbuf;

    // dw replicas (8 MB) in the not-yet-written quantized region of d_out
    // (out+16 -> 64B-aligned); zeroed by argmin, consumed by emaBF, then
    // overwritten by mix2's quantize role.
    float* dwrep = out + 16;

    epack_ee_kernel<<<16, 256, 0, stream>>>(emb_w, epack, eebuf, crep, lossac);

    argmin_mfma_kernel<<<N_VEC / 256, 256, 0, stream>>>(
        inputs, epack, eebuf, idxbuf, crep, dwrep);

    mix1_kernel<<<DW_BLOCKS + ENC_A_BLOCKS, 256, 0, stream>>>(
        inputs, idxbuf, out + ENC_OFF, dwrep);

    emaBF_kernel<<<K_CODES / 4, 256, 0, stream>>>(
        crep, ema_cs, dwrep, ema_w, nemb, out + PERP_OFF);

    mix2_kernel<<<QZ_BLOCKS + ENC_B_BLOCKS, 256, 0, stream>>>(
        inputs, idxbuf, nemb, out + Q_OFF, lossac, out + ENC_OFF);

    finalize_kernel<<<1, 1, 0, stream>>>(lossac, out);
}